// Round 6
// baseline (145.169 us; speedup 1.0000x reference)
//
#include <hip/hip_runtime.h>
#include <hip/hip_cooperative_groups.h>
#include <math.h>

namespace cg = cooperative_groups;

#define BB 32
#define LL 2048
#define DD 256
#define NC 16
#define TPB 256   // 4 waves

// ---------- cooperative fused config (512 blocks = 2 blocks/CU guaranteed) ----------
#define CSPLIT 16
#define CNBLK  (BB * CSPLIT)            // 512
#define CTOK_CHUNK (LL / CSPLIT)        // 128 tokens per block
#define CTOK_WAVE  (CTOK_CHUNK / 4)     // 32 tokens per wave
#define CPF 8                           // gathers in flight

// ---------- fallback config (R4 proven, 33 us) ----------
#define FSPLIT 32
#define FTOK_CHUNK (LL / FSPLIT)        // 64
#define FTOK_WAVE  (FTOK_CHUNK / 4)     // 16
#define FPF 8

// ws layout (floats) — shared by both paths (FSPLIT >= CSPLIT sizes):
//  pes  [32][BB][DD]  partial emb_sum
//  plen [32][BB]      partial lens
//  pout [32][BB][DD]  partial weighted sum
//  pys  [32][BB]      partial ysum
//  emb_sum [BB][DD]   (fallback only)
//  lens [BB]          (fallback only)

// ============================ cooperative fused ============================
__global__ __launch_bounds__(TPB, 2) void kFused(
    const int* __restrict__ idx, const float* __restrict__ mask,
    const float4* __restrict__ enc4, const float* __restrict__ dec_w,
    float* __restrict__ pes, float* __restrict__ plen,
    float* __restrict__ pout, float* __restrict__ pys,
    float* __restrict__ out) {
  cg::grid_group grid = cg::this_grid();
  const int b     = blockIdx.x / CSPLIT;
  const int chunk = blockIdx.x % CSPLIT;
  const int wave  = threadIdx.x >> 6;
  const int lane  = threadIdx.x & 63;
  const int tid   = threadIdx.x;
  const int l0 = chunk * CTOK_CHUNK + wave * CTOK_WAVE;

  __shared__ __align__(16) float lds[4][DD];
  __shared__ float small4[4];
  __shared__ float ysum_s, len_s;

  // ---- single gather pass: masked rows stay in registers for the whole kernel
  float  m_r[CTOK_WAVE];
  float4 w_r[CTOK_WAVE];
  #pragma unroll
  for (int g = 0; g < CTOK_WAVE; g += CPF) {
    int ids[CPF]; float ms[CPF];
    #pragma unroll
    for (int t = 0; t < CPF; ++t) {
      ids[t] = idx[b * LL + l0 + g + t];
      ms[t]  = mask[b * LL + l0 + g + t];
    }
    float4 v[CPF];
    #pragma unroll
    for (int t = 0; t < CPF; ++t)
      v[t] = enc4[(size_t)ids[t] * (DD / 4) + lane];
    #pragma unroll
    for (int t = 0; t < CPF; ++t) {
      m_r[g + t] = ms[t];
      w_r[g + t].x = v[t].x * ms[t]; w_r[g + t].y = v[t].y * ms[t];
      w_r[g + t].z = v[t].z * ms[t]; w_r[g + t].w = v[t].w * ms[t];
    }
  }

  // ---- phase A: block-partial emb_sum and lens
  {
    float4 acc = {0.f, 0.f, 0.f, 0.f};
    float lenacc = 0.f;
    #pragma unroll
    for (int t = 0; t < CTOK_WAVE; ++t) {
      acc.x += w_r[t].x; acc.y += w_r[t].y;
      acc.z += w_r[t].z; acc.w += w_r[t].w;
      lenacc += m_r[t];
    }
    lds[wave][lane * 4 + 0] = acc.x;
    lds[wave][lane * 4 + 1] = acc.y;
    lds[wave][lane * 4 + 2] = acc.z;
    lds[wave][lane * 4 + 3] = acc.w;
    if (lane == 0) small4[wave] = lenacc;
    __syncthreads();
    const float s = lds[0][tid] + lds[1][tid] + lds[2][tid] + lds[3][tid];
    pes[(chunk * BB + b) * DD + tid] = s;
    if (tid == 0) plen[chunk * BB + b] = small4[0] + small4[1] + small4[2] + small4[3];
  }

  grid.sync();

  // ---- every block reduces emb_sum[b] itself
  __syncthreads();
  {
    float es_col = 0.f;
    #pragma unroll
    for (int c = 0; c < CSPLIT; ++c) es_col += pes[(c * BB + b) * DD + tid];
    lds[0][tid] = es_col;
  }
  __syncthreads();
  const float4 es = *reinterpret_cast<const float4*>(&lds[0][lane * 4]);
  __syncthreads();

  // ---- phase B: scores + weighted sum, entirely from registers
  {
    float4 acc = {0.f, 0.f, 0.f, 0.f};
    float ys = 0.f;
    #pragma unroll
    for (int t = 0; t < CTOK_WAVE; ++t) {
      float d = w_r[t].x * es.x + w_r[t].y * es.y + w_r[t].z * es.z + w_r[t].w * es.w;
      #pragma unroll
      for (int off = 32; off > 0; off >>= 1) d += __shfl_xor(d, off);
      const float y = expf(d) * m_r[t];
      acc.x += y * w_r[t].x; acc.y += y * w_r[t].y;
      acc.z += y * w_r[t].z; acc.w += y * w_r[t].w;
      ys += y;
    }
    lds[wave][lane * 4 + 0] = acc.x;
    lds[wave][lane * 4 + 1] = acc.y;
    lds[wave][lane * 4 + 2] = acc.z;
    lds[wave][lane * 4 + 3] = acc.w;
    if (lane == 0) small4[wave] = ys;
    __syncthreads();
    const float s = lds[0][tid] + lds[1][tid] + lds[2][tid] + lds[3][tid];
    pout[(chunk * BB + b) * DD + tid] = s;
    if (tid == 0) pys[chunk * BB + b] = small4[0] + small4[1] + small4[2] + small4[3];
  }

  grid.sync();

  // ---- final: blocks 0..31 reduce partials, normalize, run the head
  if (blockIdx.x < BB) {
    const int b2 = blockIdx.x;
    float os = 0.f, s2 = 0.f;
    #pragma unroll
    for (int c = 0; c < CSPLIT; ++c) {
      os += pout[(c * BB + b2) * DD + tid];
      s2 += pes [(c * BB + b2) * DD + tid];
    }
    if (tid < 64) {
      float v = (tid < CSPLIT) ? pys[tid * BB + b2] : 0.f;
      #pragma unroll
      for (int off = 16; off > 0; off >>= 1) v += __shfl_xor(v, off);
      if (tid == 0) ysum_s = v;
    } else if (tid < 128) {
      const int t2 = tid - 64;
      float v = (t2 < CSPLIT) ? plen[t2 * BB + b2] : 0.f;
      #pragma unroll
      for (int off = 16; off > 0; off >>= 1) v += __shfl_xor(v, off);
      if (t2 == 0) len_s = v;
    }
    __syncthreads();
    lds[1][tid] = os / ysum_s + s2 / len_s;
    __syncthreads();
    const float4 vv = *reinterpret_cast<const float4*>(&lds[1][lane * 4]);
    #pragma unroll
    for (int cc = 0; cc < 4; ++cc) {
      const int c = wave * 4 + cc;
      const float4 dw = reinterpret_cast<const float4*>(dec_w)[c * (DD / 4) + lane];
      float d = vv.x * dw.x + vv.y * dw.y + vv.z * dw.z + vv.w * dw.w;
      #pragma unroll
      for (int off = 32; off > 0; off >>= 1) d += __shfl_xor(d, off);
      if (lane == 0) out[b2 * NC + c] = d;
    }
  }
}

// ============================ fallback (R4, proven) ============================
__global__ __launch_bounds__(TPB) void kA_partial(
    const int* __restrict__ idx, const float* __restrict__ mask,
    const float4* __restrict__ enc4,
    float* __restrict__ pes, float* __restrict__ plen) {
  const int b     = blockIdx.x / FSPLIT;
  const int chunk = blockIdx.x % FSPLIT;
  const int wave  = threadIdx.x >> 6;
  const int lane  = threadIdx.x & 63;
  const int tid   = threadIdx.x;
  const int l0 = chunk * FTOK_CHUNK + wave * FTOK_WAVE;

  int   id_r[FTOK_WAVE];
  float m_r[FTOK_WAVE];
  #pragma unroll
  for (int t = 0; t < FTOK_WAVE; ++t) {
    id_r[t] = idx[b * LL + l0 + t];
    m_r[t]  = mask[b * LL + l0 + t];
  }

  float4 acc = {0.f, 0.f, 0.f, 0.f};
  float lenacc = 0.f;
  #pragma unroll
  for (int g = 0; g < FTOK_WAVE; g += FPF) {
    float4 v[FPF];
    #pragma unroll
    for (int t = 0; t < FPF; ++t)
      v[t] = enc4[(size_t)id_r[g + t] * (DD / 4) + lane];
    #pragma unroll
    for (int t = 0; t < FPF; ++t) {
      const float m = m_r[g + t];
      acc.x += v[t].x * m; acc.y += v[t].y * m;
      acc.z += v[t].z * m; acc.w += v[t].w * m;
      lenacc += m;
    }
  }

  __shared__ float lds[4][DD];
  __shared__ float llds[4];
  lds[wave][lane * 4 + 0] = acc.x;
  lds[wave][lane * 4 + 1] = acc.y;
  lds[wave][lane * 4 + 2] = acc.z;
  lds[wave][lane * 4 + 3] = acc.w;
  if (lane == 0) llds[wave] = lenacc;
  __syncthreads();

  const float s = lds[0][tid] + lds[1][tid] + lds[2][tid] + lds[3][tid];
  pes[(chunk * BB + b) * DD + tid] = s;
  if (tid == 0) plen[chunk * BB + b] = llds[0] + llds[1] + llds[2] + llds[3];
}

__global__ __launch_bounds__(TPB) void kR1(
    const float* __restrict__ pes, const float* __restrict__ plen,
    float* __restrict__ emb_sum, float* __restrict__ lens) {
  const int b = blockIdx.x;
  const int tid = threadIdx.x;
  float s = 0.f;
  #pragma unroll
  for (int c = 0; c < FSPLIT; ++c) s += pes[(c * BB + b) * DD + tid];
  emb_sum[b * DD + tid] = s;
  if (tid < 64) {
    float v = (tid < FSPLIT) ? plen[tid * BB + b] : 0.f;
    #pragma unroll
    for (int off = 16; off > 0; off >>= 1) v += __shfl_xor(v, off);
    if (tid == 0) lens[b] = v;
  }
}

__global__ __launch_bounds__(TPB) void kB_partial(
    const int* __restrict__ idx, const float* __restrict__ mask,
    const float4* __restrict__ enc4, const float* __restrict__ emb_sum,
    float* __restrict__ pout, float* __restrict__ pys) {
  const int b     = blockIdx.x / FSPLIT;
  const int chunk = blockIdx.x % FSPLIT;
  const int wave  = threadIdx.x >> 6;
  const int lane  = threadIdx.x & 63;
  const int tid   = threadIdx.x;
  const int l0 = chunk * FTOK_CHUNK + wave * FTOK_WAVE;

  const float4 es = reinterpret_cast<const float4*>(emb_sum)[b * (DD / 4) + lane];

  int   id_r[FTOK_WAVE];
  float m_r[FTOK_WAVE];
  #pragma unroll
  for (int t = 0; t < FTOK_WAVE; ++t) {
    id_r[t] = idx[b * LL + l0 + t];
    m_r[t]  = mask[b * LL + l0 + t];
  }

  float4 acc = {0.f, 0.f, 0.f, 0.f};
  float ys = 0.f;
  #pragma unroll
  for (int g = 0; g < FTOK_WAVE; g += FPF) {
    float4 v[FPF];
    #pragma unroll
    for (int t = 0; t < FPF; ++t)
      v[t] = enc4[(size_t)id_r[g + t] * (DD / 4) + lane];
    #pragma unroll
    for (int t = 0; t < FPF; ++t) {
      const float m = m_r[g + t];
      float d = v[t].x * es.x + v[t].y * es.y + v[t].z * es.z + v[t].w * es.w;
      #pragma unroll
      for (int off = 32; off > 0; off >>= 1) d += __shfl_xor(d, off);
      const float score = d * m;
      const float y = expf(score) * m;
      const float ym = y * m;
      acc.x += ym * v[t].x; acc.y += ym * v[t].y;
      acc.z += ym * v[t].z; acc.w += ym * v[t].w;
      ys += y;
    }
  }

  __shared__ float lds[4][DD];
  __shared__ float ylds[4];
  lds[wave][lane * 4 + 0] = acc.x;
  lds[wave][lane * 4 + 1] = acc.y;
  lds[wave][lane * 4 + 2] = acc.z;
  lds[wave][lane * 4 + 3] = acc.w;
  if (lane == 0) ylds[wave] = ys;
  __syncthreads();

  const float s = lds[0][tid] + lds[1][tid] + lds[2][tid] + lds[3][tid];
  pout[(chunk * BB + b) * DD + tid] = s;
  if (tid == 0) pys[chunk * BB + b] = ylds[0] + ylds[1] + ylds[2] + ylds[3];
}

__global__ __launch_bounds__(TPB) void kR2head(
    const float* __restrict__ pout, const float* __restrict__ pys,
    const float* __restrict__ emb_sum, const float* __restrict__ lens,
    const float* __restrict__ dec_w, float* __restrict__ out) {
  const int b = blockIdx.x;
  const int tid = threadIdx.x;
  const int wave = tid >> 6;
  const int lane = tid & 63;

  float os = 0.f;
  #pragma unroll
  for (int c = 0; c < FSPLIT; ++c) os += pout[(c * BB + b) * DD + tid];

  __shared__ float ysum_s;
  __shared__ float vec[DD];
  if (tid < 64) {
    float v = (tid < FSPLIT) ? pys[tid * BB + b] : 0.f;
    #pragma unroll
    for (int off = 16; off > 0; off >>= 1) v += __shfl_xor(v, off);
    if (tid == 0) ysum_s = v;
  }
  __syncthreads();

  vec[tid] = os / ysum_s + emb_sum[b * DD + tid] / lens[b];
  __syncthreads();

  const float4 vv = *reinterpret_cast<const float4*>(&vec[lane * 4]);
  #pragma unroll
  for (int cc = 0; cc < 4; ++cc) {
    const int c = wave * 4 + cc;
    const float4 dw = reinterpret_cast<const float4*>(dec_w)[c * (DD / 4) + lane];
    float d = vv.x * dw.x + vv.y * dw.y + vv.z * dw.z + vv.w * dw.w;
    #pragma unroll
    for (int off = 32; off > 0; off >>= 1) d += __shfl_xor(d, off);
    if (lane == 0) out[b * NC + c] = d;
  }
}

extern "C" void kernel_launch(void* const* d_in, const int* in_sizes, int n_in,
                              void* d_out, int out_size, void* d_ws, size_t ws_size,
                              hipStream_t stream) {
  const int*    idx   = (const int*)d_in[0];
  const float*  mask  = (const float*)d_in[1];
  const float4* enc4  = (const float4*)d_in[2];
  const float*  dec_w = (const float*)d_in[3];
  float* out = (float*)d_out;

  float* ws = (float*)d_ws;
  float* pes     = ws;                        // 32*BB*DD
  float* plen    = pes + 32 * BB * DD;        // 32*BB
  float* pout    = plen + 32 * BB;            // 32*BB*DD
  float* pys     = pout + 32 * BB * DD;       // 32*BB
  float* emb_sum = pys + 32 * BB;             // BB*DD (fallback)
  float* lens    = emb_sum + BB * DD;         // BB   (fallback)

  void* args[] = { (void*)&idx, (void*)&mask, (void*)&enc4, (void*)&dec_w,
                   (void*)&pes, (void*)&plen, (void*)&pout, (void*)&pys,
                   (void*)&out };
  hipError_t err = hipLaunchCooperativeKernel((const void*)kFused,
                                              dim3(CNBLK), dim3(TPB),
                                              args, 0, stream);
  if (err != hipSuccess) {
    (void)hipGetLastError();   // clear the error state, take the proven path
    const dim3 block(TPB);
    const dim3 gridP(BB * FSPLIT);
    hipLaunchKernelGGL(kA_partial, gridP, block, 0, stream,
                       (const int*)idx, (const float*)mask, enc4, pes, plen);
    hipLaunchKernelGGL(kR1, dim3(BB), block, 0, stream, pes, plen, emb_sum, lens);
    hipLaunchKernelGGL(kB_partial, gridP, block, 0, stream,
                       (const int*)idx, (const float*)mask, enc4, emb_sum, pout, pys);
    hipLaunchKernelGGL(kR2head, dim3(BB), block, 0, stream,
                       pout, pys, emb_sum, lens, dec_w, out);
  }
}

// Round 7
// 36.156 us; speedup vs baseline: 4.0151x; 4.0151x over previous
//
#include <hip/hip_runtime.h>
#include <math.h>

#define BB 32
#define LL 2048
#define DD 256
#define NC 16
#define TPB 256   // 4 waves

// kA: 1024 blocks, 64 tokens each
#define SA 32
#define TA_CHUNK (LL / SA)        // 64
#define TA_WAVE  (TA_CHUNK / 4)   // 16

// kB: 512 blocks, 128 tokens each
#define SB 16
#define TB_CHUNK (LL / SB)        // 128
#define TB_WAVE  (TB_CHUNK / 4)   // 32
#define PFB 8                     // gathers in flight in kB

// ws layout (floats):
//  pes  [SA][BB][DD]   partial emb_sum
//  plen [SA][BB]       partial lens
//  pout [SB][BB][DD]   partial weighted sum
//  pys  [SB][BB]       partial ysum
//  emb_sum [BB][DD]
//  lens [BB]

__global__ __launch_bounds__(TPB) void kA_partial(
    const int* __restrict__ idx, const float* __restrict__ mask,
    const float4* __restrict__ enc4,
    float* __restrict__ pes, float* __restrict__ plen) {
  const int b     = blockIdx.x / SA;
  const int chunk = blockIdx.x % SA;
  const int wave  = threadIdx.x >> 6;
  const int lane  = threadIdx.x & 63;
  const int tid   = threadIdx.x;
  const int l0 = chunk * TA_CHUNK + wave * TA_WAVE;

  int   id_r[TA_WAVE];
  float m_r[TA_WAVE];
  #pragma unroll
  for (int t = 0; t < TA_WAVE; ++t) {
    id_r[t] = idx[b * LL + l0 + t];
    m_r[t]  = mask[b * LL + l0 + t];
  }
  // all 16 gathers in flight
  float4 v_r[TA_WAVE];
  #pragma unroll
  for (int t = 0; t < TA_WAVE; ++t)
    v_r[t] = enc4[(size_t)id_r[t] * (DD / 4) + lane];

  float4 acc = {0.f, 0.f, 0.f, 0.f};
  float lenacc = 0.f;
  #pragma unroll
  for (int t = 0; t < TA_WAVE; ++t) {
    const float m = m_r[t];
    acc.x += v_r[t].x * m; acc.y += v_r[t].y * m;
    acc.z += v_r[t].z * m; acc.w += v_r[t].w * m;
    lenacc += m;
  }

  __shared__ float lds[4][DD];
  __shared__ float llds[4];
  lds[wave][lane * 4 + 0] = acc.x;
  lds[wave][lane * 4 + 1] = acc.y;
  lds[wave][lane * 4 + 2] = acc.z;
  lds[wave][lane * 4 + 3] = acc.w;
  if (lane == 0) llds[wave] = lenacc;
  __syncthreads();

  const float s = lds[0][tid] + lds[1][tid] + lds[2][tid] + lds[3][tid];
  pes[(chunk * BB + b) * DD + tid] = s;
  if (tid == 0) plen[chunk * BB + b] = llds[0] + llds[1] + llds[2] + llds[3];
}

__global__ __launch_bounds__(TPB) void kB_fused(
    const int* __restrict__ idx, const float* __restrict__ mask,
    const float4* __restrict__ enc4,
    const float* __restrict__ pes, const float* __restrict__ plen,
    float* __restrict__ pout, float* __restrict__ pys,
    float* __restrict__ emb_sum, float* __restrict__ lens) {
  const int b     = blockIdx.x / SB;
  const int chunk = blockIdx.x % SB;
  const int wave  = threadIdx.x >> 6;
  const int lane  = threadIdx.x & 63;
  const int tid   = threadIdx.x;
  const int l0 = chunk * TB_CHUNK + wave * TB_WAVE;

  __shared__ __align__(16) float esb[DD];
  __shared__ float lds[4][DD];
  __shared__ float ylds[4];

  // ---- fold former kR1: every block reduces emb_sum[b] from partials
  {
    float es_col = 0.f;
    #pragma unroll
    for (int c = 0; c < SA; ++c) es_col += pes[(c * BB + b) * DD + tid];
    esb[tid] = es_col;
    if (chunk == 0) {
      emb_sum[b * DD + tid] = es_col;          // for the head kernel
      if (tid < 64) {
        float v = (tid < SA) ? plen[tid * BB + b] : 0.f;
        #pragma unroll
        for (int off = 16; off > 0; off >>= 1) v += __shfl_xor(v, off);
        if (tid == 0) lens[b] = v;
      }
    }
  }
  __syncthreads();
  const float4 es = *reinterpret_cast<const float4*>(&esb[lane * 4]);

  int   id_r[TB_WAVE];
  float m_r[TB_WAVE];
  #pragma unroll
  for (int t = 0; t < TB_WAVE; ++t) {
    id_r[t] = idx[b * LL + l0 + t];
    m_r[t]  = mask[b * LL + l0 + t];
  }

  float4 acc = {0.f, 0.f, 0.f, 0.f};
  float ys = 0.f;
  #pragma unroll
  for (int g = 0; g < TB_WAVE; g += PFB) {
    float4 v[PFB];
    #pragma unroll
    for (int t = 0; t < PFB; ++t)
      v[t] = enc4[(size_t)id_r[g + t] * (DD / 4) + lane];
    #pragma unroll
    for (int t = 0; t < PFB; ++t) {
      const float m = m_r[g + t];
      float d = v[t].x * es.x + v[t].y * es.y + v[t].z * es.z + v[t].w * es.w;
      #pragma unroll
      for (int off = 32; off > 0; off >>= 1) d += __shfl_xor(d, off);
      const float score = d * m;        // emb_l . emb_sum   (emb_l = m*row)
      const float y = expf(score) * m;  // y = exp(score) * mask
      const float ym = y * m;           // weight on raw row
      acc.x += ym * v[t].x; acc.y += ym * v[t].y;
      acc.z += ym * v[t].z; acc.w += ym * v[t].w;
      ys += y;                          // identical across lanes
    }
  }

  lds[wave][lane * 4 + 0] = acc.x;
  lds[wave][lane * 4 + 1] = acc.y;
  lds[wave][lane * 4 + 2] = acc.z;
  lds[wave][lane * 4 + 3] = acc.w;
  if (lane == 0) ylds[wave] = ys;
  __syncthreads();

  const float s = lds[0][tid] + lds[1][tid] + lds[2][tid] + lds[3][tid];
  pout[(chunk * BB + b) * DD + tid] = s;
  if (tid == 0) pys[chunk * BB + b] = ylds[0] + ylds[1] + ylds[2] + ylds[3];
}

__global__ __launch_bounds__(TPB) void kR2head(
    const float* __restrict__ pout, const float* __restrict__ pys,
    const float* __restrict__ emb_sum, const float* __restrict__ lens,
    const float* __restrict__ dec_w, float* __restrict__ out) {
  const int b = blockIdx.x;
  const int tid = threadIdx.x;
  const int wave = tid >> 6;
  const int lane = tid & 63;

  float os = 0.f;
  #pragma unroll
  for (int c = 0; c < SB; ++c) os += pout[(c * BB + b) * DD + tid];

  __shared__ float ysum_s;
  __shared__ __align__(16) float vec[DD];
  if (tid < 64) {
    float v = (tid < SB) ? pys[tid * BB + b] : 0.f;
    #pragma unroll
    for (int off = 16; off > 0; off >>= 1) v += __shfl_xor(v, off);
    if (tid == 0) ysum_s = v;
  }
  __syncthreads();

  vec[tid] = os / ysum_s + emb_sum[b * DD + tid] / lens[b];
  __syncthreads();

  // head: wave w computes classes 4w .. 4w+3
  const float4 vv = *reinterpret_cast<const float4*>(&vec[lane * 4]);
  #pragma unroll
  for (int cc = 0; cc < 4; ++cc) {
    const int c = wave * 4 + cc;
    const float4 dw = reinterpret_cast<const float4*>(dec_w)[c * (DD / 4) + lane];
    float d = vv.x * dw.x + vv.y * dw.y + vv.z * dw.z + vv.w * dw.w;
    #pragma unroll
    for (int off = 32; off > 0; off >>= 1) d += __shfl_xor(d, off);
    if (lane == 0) out[b * NC + c] = d;
  }
}

extern "C" void kernel_launch(void* const* d_in, const int* in_sizes, int n_in,
                              void* d_out, int out_size, void* d_ws, size_t ws_size,
                              hipStream_t stream) {
  const int*    idx   = (const int*)d_in[0];
  const float*  mask  = (const float*)d_in[1];
  const float4* enc4  = (const float4*)d_in[2];
  const float*  dec_w = (const float*)d_in[3];
  float* out = (float*)d_out;

  float* ws = (float*)d_ws;
  float* pes     = ws;                        // SA*BB*DD
  float* plen    = pes + SA * BB * DD;        // SA*BB
  float* pout    = plen + SA * BB;            // SB*BB*DD
  float* pys     = pout + SB * BB * DD;       // SB*BB
  float* emb_sum = pys + SB * BB;             // BB*DD
  float* lens    = emb_sum + BB * DD;         // BB

  const dim3 block(TPB);
  hipLaunchKernelGGL(kA_partial, dim3(BB * SA), block, 0, stream,
                     idx, mask, enc4, pes, plen);
  hipLaunchKernelGGL(kB_fused, dim3(BB * SB), block, 0, stream,
                     idx, mask, enc4, pes, plen, pout, pys, emb_sum, lens);
  hipLaunchKernelGGL(kR2head, dim3(BB), block, 0, stream,
                     pout, pys, emb_sum, lens, dec_w, out);
}